// Round 3
// baseline (44.176 us; speedup 1.0000x reference)
//
#include <hip/hip_runtime.h>
#include <hip/hip_cooperative_groups.h>
#include <math.h>

namespace cg = cooperative_groups;

// RelativeDepthLoss — H=W=64, N=4096, f32 in, f32 scalar out.
// Single cooperative kernel, 256 blocks x 256 threads (1 block/CU):
//   block b: i-strip = pixels [16b,16b+16) (one row segment, row ri=b>>2),
//            j = all 4096. thread t: i = 16b+(t&15), j-slice = [(t>>4)*256, +256).
//   LDS: djw[4096] (pred-gt, mask) as float2, padded +2 float2 per 256 to
//        de-alias the 4 jq-groups of a wave (stride 258*2 banks = 4 apart);
//        tbl[64][130]: 1/(sqrt(dr^2+dc^2)+0.001), row stride 130 so the 4
//        jq-group rows land 8 banks apart (2-way max = free).
//   grad: sobel of (pred-gt) by linearity, 16 px/block from LDS, zero-pad edges.
//   partials -> ws slots (plain stores), grid.sync(), block 0 reduces + writes out.
// No ws state carried across calls: every slot is written every call.

#define IDX(j) ((j) + (((j) >> 8) << 1))   // djw padding: +2 float2 per 256 entries

__global__ __launch_bounds__(256) void fused(const float* __restrict__ pred,
                                             const float* __restrict__ gt,
                                             const int* __restrict__ mask,
                                             float* __restrict__ ws,
                                             float* __restrict__ out) {
    __shared__ float2 djw[4096 + 32];
    __shared__ float  tbl[64 * 130];
    __shared__ float  red[12];

    const int t = threadIdx.x;
    const int b = blockIdx.x;

    // ---- stage d = pred-gt, w = mask (vectorized 16B loads) ----
    for (int m = 0; m < 4; ++m) {
        const int q = (m << 8) + t;                    // float4 index
        const float4 p4 = ((const float4*)pred)[q];
        const float4 g4 = ((const float4*)gt)[q];
        const int4   m4 = ((const int4*)mask)[q];
        const int o = IDX(q << 2);                     // (j>>8) const across the 4
        djw[o + 0] = make_float2(p4.x - g4.x, m4.x ? 1.f : 0.f);
        djw[o + 1] = make_float2(p4.y - g4.y, m4.y ? 1.f : 0.f);
        djw[o + 2] = make_float2(p4.z - g4.z, m4.z ? 1.f : 0.f);
        djw[o + 3] = make_float2(p4.w - g4.w, m4.w ? 1.f : 0.f);
    }
    // ---- reciprocal-distance table (exact sqrt + div) ----
    for (int k = t; k < 64 * 128; k += 256) {
        const int   row = k >> 7;
        const float dr  = (float)row;
        const float dc  = (float)((k & 127) - 63);
        tbl[row * 130 + (k & 127)] = 1.f / (sqrtf(dr * dr + dc * dc) + 0.001f);
    }
    __syncthreads();

    // ---- pairwise: 256 pairs per thread ----
    const int    i   = (b << 4) + (t & 15);
    const float2 dwi = djw[IDX(i)];
    const float  di  = dwi.x, wi = dwi.y;
    const int    ri  = b >> 2;
    const int    ci  = i & 63;
    const int    jq  = t >> 4;

    float acc = 0.f;
    const float2* dp = &djw[(jq << 8) + (jq << 1)];    // IDX(jq*256)
    for (int r4 = 0; r4 < 4; ++r4) {
        const int rj  = (jq << 2) + r4;
        const int row = abs(ri - rj);
        const float*  trow = &tbl[row * 130 + 63 - ci]; // +cj = immediate offsets
        const float2* dpr  = dp + (r4 << 6);
#pragma unroll 16
        for (int cj = 0; cj < 64; ++cj) {
            const float2 dw = dpr[cj];
            acc += fabsf(di - dw.x) * (dw.y * trow[cj]);
        }
    }
    acc *= wi;

    // ---- sobel grad for this block's 16 pixels (from LDS, zero-pad) ----
    float gp = 0.f, mp = 0.f;
    if (t < 16) {
        const int k = (b << 4) + t;
        const int r = k >> 6, c = k & 63;
        const float x00 = (r > 0  && c > 0 ) ? djw[IDX(k - 65)].x : 0.f;
        const float x01 = (r > 0           ) ? djw[IDX(k - 64)].x : 0.f;
        const float x02 = (r > 0  && c < 63) ? djw[IDX(k - 63)].x : 0.f;
        const float x10 = (          c > 0 ) ? djw[IDX(k - 1 )].x : 0.f;
        const float x12 = (          c < 63) ? djw[IDX(k + 1 )].x : 0.f;
        const float x20 = (r < 63 && c > 0 ) ? djw[IDX(k + 63)].x : 0.f;
        const float x21 = (r < 63          ) ? djw[IDX(k + 64)].x : 0.f;
        const float x22 = (r < 63 && c < 63) ? djw[IDX(k + 65)].x : 0.f;
        const float gx = (x02 - x00) + 2.f * (x12 - x10) + (x22 - x20);
        const float gy = (x20 - x00) + 2.f * (x21 - x01) + (x22 - x02);
        mp = djw[IDX(k)].y;
        gp = mp * (fabsf(gx) + fabsf(gy));
    }

    // ---- block reduction (3 values) ----
    for (int off = 32; off > 0; off >>= 1) {
        acc += __shfl_down(acc, off, 64);
        gp  += __shfl_down(gp,  off, 64);
        mp  += __shfl_down(mp,  off, 64);
    }
    const int wv = t >> 6;
    if ((t & 63) == 0) { red[wv] = acc; red[4 + wv] = gp; red[8 + wv] = mp; }
    __syncthreads();
    if (t == 0) {
        ws[b]       = red[0] + red[1] + red[2]  + red[3];
        ws[256 + b] = red[4] + red[5] + red[6]  + red[7];
        ws[512 + b] = red[8] + red[9] + red[10] + red[11];
    }

    cg::this_grid().sync();

    // ---- block 0 finalizes ----
    if (b == 0) {
        float p = ws[t], g = ws[256 + t], m = ws[512 + t];
        for (int off = 32; off > 0; off >>= 1) {
            p += __shfl_down(p, off, 64);
            g += __shfl_down(g, off, 64);
            m += __shfl_down(m, off, 64);
        }
        if ((t & 63) == 0) { red[wv] = p; red[4 + wv] = g; red[8 + wv] = m; }
        __syncthreads();
        if (t == 0) {
            p = red[0] + red[1] + red[2]  + red[3];
            g = red[4] + red[5] + red[6]  + red[7];
            m = red[8] + red[9] + red[10] + red[11];
            const float grad_loss = g / m;
            const float pair_loss = p / sqrtf(m * m + 1e-5f);
            out[0] = logf(0.5f * grad_loss + 0.5f * pair_loss + 1.f);
        }
    }
}

extern "C" void kernel_launch(void* const* d_in, const int* in_sizes, int n_in,
                              void* d_out, int out_size, void* d_ws, size_t ws_size,
                              hipStream_t stream) {
    const float* pred = (const float*)d_in[0];
    const float* gt   = (const float*)d_in[1];
    const int*   msk  = (const int*)d_in[2];
    float* ws  = (float*)d_ws;
    float* out = (float*)d_out;

    void* args[] = { (void*)&pred, (void*)&gt, (void*)&msk, (void*)&ws, (void*)&out };
    hipLaunchCooperativeKernel((void*)fused, dim3(256), dim3(256), args, 0, stream);
}

// Round 4
// 28.520 us; speedup vs baseline: 1.5489x; 1.5489x over previous
//
#include <hip/hip_runtime.h>
#include <math.h>

// RelativeDepthLoss — H=W=64, N=4096, f32 in, f32 scalar out.
// Structure (R2-proven): hipMemsetAsync(16B) + ONE kernel, 256 blocks x 256 thr.
//   block b: i-strip = pixels [16b,16b+16) (all in image row ri=b>>2).
//   wave w (0..3) owns i-quad iq=16b+4w..+3; lane l covers image row l (j=64l..64l+63).
//   Inner loop (fully unrolled 64x): 1 ds_read_b64 (d_j,w_j) + 12 VALU for 4 pairs.
//   Reciprocal-distance values come from a COMPILE-TIME table GT[64][136]
//   (1/(sqrt(dr^2+dc^2)+0.001), dc=c-66), 72 entries preloaded per lane into
//   registers (18x global_load_dwordx4, L2-resident, 16B-aligned by construction).
//   Grad: sobel of (pred-gt) by linearity, 16 px/block, from LDS.
//   Finalize: atomics + counter; last block writes out. ws[0..3] zeroed per call.

#define IDX(j) ((j) + ((j) >> 6))   // djw padding: +1 float2 per 64 (stride 65)

// ---- compile-time inverse-distance table ----
struct alignas(16) InvDistTable {
    float v[64][136];               // row stride 136 floats = 544 B (16B multiple)
    constexpr InvDistTable() : v{} {
        for (int r = 0; r < 64; ++r)
            for (int c = 0; c < 136; ++c) {
                const double dr = (double)r;
                const double dc = (double)(c - 66);
                const double x  = dr * dr + dc * dc;
                double s = 0.0;
                if (x > 0.0) {
                    double g = x;
                    for (int it = 0; it < 48; ++it) g = 0.5 * (g + x / g);
                    s = g;
                }
                v[r][c] = (float)(1.0 / (s + 0.001));
            }
    }
};
__device__ constexpr InvDistTable GT{};

__global__ __launch_bounds__(256) void fused(const float* __restrict__ pred,
                                             const float* __restrict__ gt,
                                             const int* __restrict__ mask,
                                             float* __restrict__ ws,
                                             float* __restrict__ out) {
    __shared__ float2 djw[4096 + 64];
    __shared__ float  red[12];

    const int t = threadIdx.x;
    const int b = blockIdx.x;

    // ---- stage d = pred-gt, w = mask (float4 loads, 16 px/thread) ----
    for (int m = 0; m < 4; ++m) {
        const int q = (m << 8) + t;                    // float4 index
        const float4 p4 = ((const float4*)pred)[q];
        const float4 g4 = ((const float4*)gt)[q];
        const int4   m4 = ((const int4*)mask)[q];
        const int o = IDX(q << 2);                     // same 64-group for all 4
        djw[o + 0] = make_float2(p4.x - g4.x, m4.x ? 1.f : 0.f);
        djw[o + 1] = make_float2(p4.y - g4.y, m4.y ? 1.f : 0.f);
        djw[o + 2] = make_float2(p4.z - g4.z, m4.z ? 1.f : 0.f);
        djw[o + 3] = make_float2(p4.w - g4.w, m4.w ? 1.f : 0.f);
    }

    // ---- per-lane register table preload (runs before barrier; no LDS dep) ----
    const int wv  = t >> 6;
    const int l   = t & 63;                            // lane = j image row
    const int iq  = (b << 4) + (wv << 2);              // wave's i-quad base
    const int ri  = b >> 2;
    const int ci0 = iq & 63;                           // multiple of 4
    const int row = (ri >= l) ? (ri - l) : (l - ri);
    const int c0  = 60 - ci0;                          // %4==0 -> 16B aligned

    float rt[72];
    {
        const float4* g4p = (const float4*)&GT.v[row][c0];
#pragma unroll
        for (int q = 0; q < 18; ++q) {
            const float4 f = g4p[q];
            rt[4 * q + 0] = f.x; rt[4 * q + 1] = f.y;
            rt[4 * q + 2] = f.z; rt[4 * q + 3] = f.w;
        }
    }
    __syncthreads();

    // ---- pairwise: 4 i's x 64 j's per lane, fully unrolled ----
    const float2 dwi0 = djw[IDX(iq + 0)];
    const float2 dwi1 = djw[IDX(iq + 1)];
    const float2 dwi2 = djw[IDX(iq + 2)];
    const float2 dwi3 = djw[IDX(iq + 3)];
    const float2* dp = &djw[65 * l];                   // IDX(64*l)

    float acc0 = 0.f, acc1 = 0.f, acc2 = 0.f, acc3 = 0.f;
#pragma unroll
    for (int cj = 0; cj < 64; ++cj) {
        const float2 dw = dp[cj];
        const float  w  = dw.y;
        // rt[m], m = cj + 6 - k  <=>  GT col = (cj - ci) + 66, ci = ci0 + k
        acc0 = fmaf(fabsf(dwi0.x - dw.x), rt[cj + 6] * w, acc0);
        acc1 = fmaf(fabsf(dwi1.x - dw.x), rt[cj + 5] * w, acc1);
        acc2 = fmaf(fabsf(dwi2.x - dw.x), rt[cj + 4] * w, acc2);
        acc3 = fmaf(fabsf(dwi3.x - dw.x), rt[cj + 3] * w, acc3);
    }
    float acc = dwi0.y * acc0 + dwi1.y * acc1 + dwi2.y * acc2 + dwi3.y * acc3;

    // ---- sobel grad for this block's 16 pixels (zero-pad edges) ----
    float gp = 0.f, mp = 0.f;
    if (t < 16) {
        const int k = (b << 4) + t;
        const int r = k >> 6, c = k & 63;
        const float x00 = (r > 0  && c > 0 ) ? djw[IDX(k - 65)].x : 0.f;
        const float x01 = (r > 0           ) ? djw[IDX(k - 64)].x : 0.f;
        const float x02 = (r > 0  && c < 63) ? djw[IDX(k - 63)].x : 0.f;
        const float x10 = (          c > 0 ) ? djw[IDX(k - 1 )].x : 0.f;
        const float x12 = (          c < 63) ? djw[IDX(k + 1 )].x : 0.f;
        const float x20 = (r < 63 && c > 0 ) ? djw[IDX(k + 63)].x : 0.f;
        const float x21 = (r < 63          ) ? djw[IDX(k + 64)].x : 0.f;
        const float x22 = (r < 63 && c < 63) ? djw[IDX(k + 65)].x : 0.f;
        const float gx = (x02 - x00) + 2.f * (x12 - x10) + (x22 - x20);
        const float gy = (x20 - x00) + 2.f * (x21 - x01) + (x22 - x02);
        mp = djw[IDX(k)].y;
        gp = mp * (fabsf(gx) + fabsf(gy));
    }

    // ---- block reduction (3 values) ----
    for (int off = 32; off > 0; off >>= 1) {
        acc += __shfl_down(acc, off, 64);
        gp  += __shfl_down(gp,  off, 64);
        mp  += __shfl_down(mp,  off, 64);
    }
    if (l == 0) { red[wv] = acc; red[4 + wv] = gp; red[8 + wv] = mp; }
    __syncthreads();

    // ---- publish; last-finished block finalizes ----
    if (t == 0) {
        atomicAdd(&ws[0], red[0] + red[1] + red[2]  + red[3]);
        atomicAdd(&ws[1], red[4] + red[5] + red[6]  + red[7]);
        atomicAdd(&ws[2], red[8] + red[9] + red[10] + red[11]);
        __threadfence();
        const unsigned old = atomicAdd((unsigned*)(ws + 3), 1u);
        if (old == 255u) {
            const float pair = atomicAdd(&ws[0], 0.f);
            const float gnum = atomicAdd(&ws[1], 0.f);
            const float msum = atomicAdd(&ws[2], 0.f);
            const float grad_loss = gnum / msum;
            const float pair_loss = pair / sqrtf(msum * msum + 1e-5f);
            out[0] = logf(0.5f * grad_loss + 0.5f * pair_loss + 1.f);
        }
    }
}

extern "C" void kernel_launch(void* const* d_in, const int* in_sizes, int n_in,
                              void* d_out, int out_size, void* d_ws, size_t ws_size,
                              hipStream_t stream) {
    const float* pred = (const float*)d_in[0];
    const float* gt   = (const float*)d_in[1];
    const int*   msk  = (const int*)d_in[2];
    float* ws  = (float*)d_ws;
    float* out = (float*)d_out;

    hipMemsetAsync(d_ws, 0, 16, stream);   // zero pair/grad/mask accumulators + counter
    fused<<<256, 256, 0, stream>>>(pred, gt, msk, ws, out);
}